// Round 1
// 859.105 us; speedup vs baseline: 1.0653x; 1.0653x over previous
//
#include <hip/hip_runtime.h>
#include <cstdio>
#include <cstdint>

// HeteroGraph 3-layer SAGE on MI355X — R6.
// R5 post-mortem: kaggAU latency-bound (bf16 cut traffic 23%, time -3%;
// 2.5 TB/s << ceilings, VALUBusy 24%). Old gather: 8 edges per serialized
// latency window (64 lanes x 2B per row). R6: 8 lanes x 16B per row ->
// 8 edges per load instruction, 32 edges in flight per window; per-dst
// cross-group combine via 3x shfl_xor. Same line-granule traffic.

#define NSUB 200000
#define NAGR 400000
#define NURB 200000
#define HDIM 64
#define ESS 2000000
#define EAS 4000000
#define EUS 2000000
#define NB 512
#define CAP_AS 8608
#define CAP_SS 4320
#define CAP_US 4320
#define CHUNK 4096
#define NCH_AS 977
#define NCH_SS 489
#define NCH_US 489
#define CDIV(a,b) (((a)+(b)-1)/(b))

using u16 = unsigned short;
typedef __attribute__((ext_vector_type(8))) short v8s;
typedef __attribute__((ext_vector_type(4))) float v4f;
typedef __attribute__((ext_vector_type(4))) unsigned int v4u;

__device__ __forceinline__ float bu2f(u16 u){
  union { unsigned int i; float f; } c; c.i = ((unsigned int)u) << 16; return c.f;
}
__device__ __forceinline__ u16 f2bu(float x){
  union { float f; unsigned int i; } c; c.f = x;
  unsigned int r = c.i + 0x7fffu + ((c.i >> 16) & 1u);
  return (u16)(r >> 16);
}
__device__ __forceinline__ int bucket_of(int d){
  return (int)(((unsigned long long)(unsigned)d * NB) / NSUB);
}
__device__ __forceinline__ int bucket_base(int b){
  return (int)(((unsigned long long)b * NSUB + NB - 1) / NB);
}

__global__ void kcast(const float4* __restrict__ in, uint2* __restrict__ outp, int n4){
  int i = blockIdx.x*256 + threadIdx.x;
  if(i<n4){
    float4 v = in[i];
    uint2 o;
    o.x = (unsigned int)f2bu(v.x) | ((unsigned int)f2bu(v.y)<<16);
    o.y = (unsigned int)f2bu(v.z) | ((unsigned int)f2bu(v.w)<<16);
    outp[i]=o;
  }
}

// fused cast of x_agr and x_urb -> bf16 (runs AFTER ksort; dst aliases pXX)
__global__ void kcast2(const float4* __restrict__ a, uint2* __restrict__ oa, int n4a,
                       const float4* __restrict__ u, uint2* __restrict__ ou, int n4u){
  int i = blockIdx.x*256 + threadIdx.x;
  const float4* src; uint2* dst; int idx;
  if(i < n4a){ src=a; dst=oa; idx=i; }
  else { idx = i - n4a; if(idx >= n4u) return; src=u; dst=ou; }
  float4 v = src[idx];
  uint2 o;
  o.x = (unsigned int)f2bu(v.x) | ((unsigned int)f2bu(v.y)<<16);
  o.y = (unsigned int)f2bu(v.z) | ((unsigned int)f2bu(v.w)<<16);
  dst[idx]=o;
}

// Per-layer weights -> bf16 transposed [o][k=256] (+bias sum); also zeros gcur.
__global__ void kprep(const float* __restrict__ Wl, const float* __restrict__ Wr,
                      const float* __restrict__ bl, u16* __restrict__ Wg,
                      float* __restrict__ bsum, int* __restrict__ gcur){
  int l = blockIdx.x, tid = threadIdx.x;
  for(int i=tid; i<16384; i+=256){
    int o = i>>8, k = i&255, a = k>>6, kk = k&63;
    float v;
    if(a<3) v = Wl[(((size_t)l*3+a)*64+o)*64+kk];
    else    v = Wr[(((size_t)l*3+0)*64+o)*64+kk]
              + Wr[(((size_t)l*3+1)*64+o)*64+kk]
              + Wr[(((size_t)l*3+2)*64+o)*64+kk];
    Wg[((size_t)l*64+o)*256 + k] = f2bu(v);
  }
  if(tid<64) bsum[l*64+tid] = bl[(l*3+0)*64+tid] + bl[(l*3+1)*64+tid] + bl[(l*3+2)*64+tid];
  for(int i=tid;i<NB;i+=256) gcur[l*NB+i]=0;
}

// Fused 3-relation bucket partition (validated R3/R4).
__global__ __launch_bounds__(256) void kpart(
    const int* __restrict__ e_ss, const int* __restrict__ e_as_s,
    const int* __restrict__ e_as_d, const int* __restrict__ e_us,
    unsigned* __restrict__ pAS, unsigned* __restrict__ pSS,
    unsigned* __restrict__ pUS, int* __restrict__ gcur){
  __shared__ int cnt[NB];
  __shared__ int seg[NB];
  int bid = blockIdx.x, tid = threadIdx.x;
  int rel, chunk, cap, Erel;
  const int *sp, *dp; unsigned* part;
  if(bid < NCH_AS){ rel=0; chunk=bid; sp=e_as_s; dp=e_as_d; part=pAS; cap=CAP_AS; Erel=EAS; }
  else if(bid < NCH_AS+NCH_SS){ rel=1; chunk=bid-NCH_AS; sp=e_ss; dp=e_ss+ESS; part=pSS; cap=CAP_SS; Erel=ESS; }
  else { rel=2; chunk=bid-NCH_AS-NCH_SS; sp=e_us; dp=e_us+EUS; part=pUS; cap=CAP_US; Erel=EUS; }
  int m = Erel - chunk*CHUNK; if(m>CHUNK) m=CHUNK;
  for(int i=tid;i<NB;i+=256) cnt[i]=0;
  __syncthreads();
  unsigned pk[16], meta[16];
  #pragma unroll
  for(int j=0;j<16;j++){
    int idx = j*256+tid;
    meta[j] = 0xFFFFFFFFu;
    if(idx < m){
      long i = (long)chunk*CHUNK + idx;
      int s = sp[i], d = dp[i];
      int b = bucket_of(d);
      int r = atomicAdd(&cnt[b],1);
      pk[j] = ((unsigned)s<<9) | (unsigned)(d - bucket_base(b));
      meta[j] = ((unsigned)b<<16) | (unsigned)r;
    }
  }
  __syncthreads();
  for(int q=tid;q<NB;q+=256){
    int c = cnt[q];
    seg[q] = c ? atomicAdd(&gcur[rel*NB+q], c) : 0;
  }
  __syncthreads();
  #pragma unroll
  for(int j=0;j<16;j++){
    if(meta[j]!=0xFFFFFFFFu){
      int b = meta[j]>>16, r = meta[j]&0xFFFF;
      int pos = seg[b] + r;
      if(pos < cap) part[(long)b*cap + pos] = pk[j];
    }
  }
}

// Exclusive scan of clamped bucket sizes -> per-bucket col base offsets.
__global__ void kbscan(const int* __restrict__ gcur, int* __restrict__ boff){
  __shared__ int s1[256];
  int t = threadIdx.x;
  for(int rel=0; rel<3; rel++){
    int cap = (rel==0)?CAP_AS:((rel==1)?CAP_SS:CAP_US);
    int g0 = gcur[rel*NB + 2*t], g1 = gcur[rel*NB + 2*t+1];
    int a0 = g0<cap?g0:cap, a1 = g1<cap?g1:cap;
    s1[t] = a0+a1;
    __syncthreads();
    for(int off=1; off<256; off<<=1){
      int x = s1[t];
      int y = (t>=off)?s1[t-off]:0;
      __syncthreads();
      s1[t] = x+y;
      __syncthreads();
    }
    int e2 = s1[t]-(a0+a1);
    boff[rel*NB + 2*t]   = e2;
    boff[rel*NB + 2*t+1] = e2+a0;
    __syncthreads();
  }
}

// Per-bucket counting sort -> CSR (validated R4).
__global__ __launch_bounds__(256) void ksort(
    const unsigned* __restrict__ pAS, const unsigned* __restrict__ pSS,
    const unsigned* __restrict__ pUS, const int* __restrict__ gcur,
    const int* __restrict__ boff,
    int* __restrict__ colAS, int* __restrict__ colSS, int* __restrict__ colUS,
    int* __restrict__ rpAS, int* __restrict__ rpSS, int* __restrict__ rpUS,
    int* __restrict__ degAS, int* __restrict__ degSS, int* __restrict__ degUS){
  __shared__ int degl[512];
  __shared__ int excl[512];
  __shared__ int cur[512];
  __shared__ int s1[256];
  int bid = blockIdx.x;
  int rel = bid >> 9, b = bid & 511;
  const unsigned* part; int cap; int* col; int* rp; int* deg;
  if(rel==0){ part=pAS; cap=CAP_AS; col=colAS; rp=rpAS; deg=degAS; }
  else if(rel==1){ part=pSS; cap=CAP_SS; col=colSS; rp=rpSS; deg=degSS; }
  else { part=pUS; cap=CAP_US; col=colUS; rp=rpUS; deg=degUS; }
  int tid = threadIdx.x;
  int base_b = bucket_base(b);
  int base_n = (b+1==NB)?NSUB:bucket_base(b+1);
  int width = base_n - base_b;
  int size = gcur[rel*NB+b]; if(size>cap) size=cap;
  int bo = boff[rel*NB+b];
  const unsigned* pb = part + (long)b*cap;
  degl[tid]=0; degl[256+tid]=0;
  __syncthreads();
  for(int i=tid;i<size;i+=256) atomicAdd(&degl[pb[i]&511u],1);
  __syncthreads();
  int a0=degl[2*tid], a1=degl[2*tid+1];
  s1[tid]=a0+a1;
  __syncthreads();
  for(int off=1; off<256; off<<=1){
    int x=s1[tid];
    int y=(tid>=off)?s1[tid-off]:0;
    __syncthreads();
    s1[tid]=x+y;
    __syncthreads();
  }
  int e2 = s1[tid]-(a0+a1);
  excl[2*tid]=e2;     excl[2*tid+1]=e2+a0;
  cur[2*tid]=e2;      cur[2*tid+1]=e2+a0;
  __syncthreads();
  for(int n=tid;n<width;n+=256){
    rp[base_b+n]  = bo + excl[n];
    deg[base_b+n] = degl[n];
  }
  for(int i=tid;i<size;i+=256){
    unsigned p = pb[i];
    int dl = (int)(p&511u);
    int r = atomicAdd(&cur[dl],1);
    col[bo + r] = (int)(p>>9);
  }
}

__device__ __forceinline__ float gather1(const float* x, size_t idx){ return x[idx]; }
__device__ __forceinline__ float gather1(const u16* x, size_t idx){ return bu2f(x[idx]); }

// Legacy scalar path (f32 fallback only): wave-per-dst, 2B/lane.
template<typename T, bool MEAN>
__device__ __forceinline__ void agg_one(const T* __restrict__ x,
    const int* __restrict__ rowptr, const int* __restrict__ deg,
    const int* __restrict__ col, u16* __restrict__ out, int w, int lane){
  int s = __builtin_amdgcn_readfirstlane(rowptr[w]);
  int d = __builtin_amdgcn_readfirstlane(deg[w]);
  float acc = 0.f;
  int i=0;
  for(; i+8<=d; i+=8){
    int sj[8];
    #pragma unroll
    for(int j=0;j<8;j++) sj[j]=col[s+i+j];
    float a[8];
    #pragma unroll
    for(int j=0;j<8;j++) a[j]=gather1(x,(size_t)sj[j]*HDIM+lane);
    acc += ((a[0]+a[1])+(a[2]+a[3])) + ((a[4]+a[5])+(a[6]+a[7]));
  }
  for(; i<d; i++) acc += gather1(x,(size_t)col[s+i]*HDIM+lane);
  float sc = 1.f;
  if(MEAN) sc = 1.f/(float)(d>1?d:1);
  out[(size_t)w*HDIM + lane] = f2bu(acc*sc);
}

// R6 fast bf16 path: 8 lanes per row (16B each), 8 edges per load instr,
// unroll 4 -> 32 edges per latency window. Group g=lane>>3 handles edge
// subset {i: i%8==g}; q=lane&7 owns elems [8q,8q+8). Combine groups with
// 3x shfl_xor at the end (once per dst).
template<bool MEAN>
__device__ __forceinline__ void agg_fast(const u16* __restrict__ x,
    const int* __restrict__ rowptr, const int* __restrict__ deg,
    const int* __restrict__ col, u16* __restrict__ out, int w, int lane){
  int s = __builtin_amdgcn_readfirstlane(rowptr[w]);
  int d = __builtin_amdgcn_readfirstlane(deg[w]);
  int g = lane>>3, q = lane&7;
  const u16* xq = x + (size_t)((unsigned)q<<3);
  float acc[8] = {0.f,0.f,0.f,0.f,0.f,0.f,0.f,0.f};
  for(int i=0; i<d; i+=32){
    int cj[4];
    #pragma unroll
    for(int j=0;j<4;j++){
      int e = i + j*8 + g;
      cj[j] = (e<d) ? col[s+e] : -1;
    }
    v8s vv[4];
    #pragma unroll
    for(int j=0;j<4;j++){
      v8s z = {};
      vv[j] = z;
      if(cj[j]>=0) vv[j] = *(const v8s*)(xq + (size_t)(unsigned)cj[j]*HDIM);
    }
    #pragma unroll
    for(int j=0;j<4;j++){
      #pragma unroll
      for(int k=0;k<8;k++) acc[k] += bu2f((u16)vv[j][k]);
    }
  }
  #pragma unroll
  for(int k=0;k<8;k++){
    float v = acc[k];
    v += __shfl_xor(v, 8);
    v += __shfl_xor(v, 16);
    v += __shfl_xor(v, 32);
    acc[k] = v;
  }
  float sc = 1.f;
  if(MEAN) sc = 1.f/(float)(d>1?d:1);
  if(g==0){
    v4u r;
    #pragma unroll
    for(int k=0;k<4;k++)
      r[k] = (unsigned)f2bu(acc[2*k]*sc) | ((unsigned)f2bu(acc[2*k+1]*sc)<<16);
    *(v4u*)(out + (size_t)w*HDIM + ((unsigned)q<<3)) = r;
  }
}

template<typename T, bool MEAN>
__device__ __forceinline__ void agg_dispatch(const T* __restrict__ x,
    const int* __restrict__ rowptr, const int* __restrict__ deg,
    const int* __restrict__ col, u16* __restrict__ out, int w, int lane){
  if constexpr (sizeof(T)==2) agg_fast<MEAN>(x, rowptr, deg, col, out, w, lane);
  else                        agg_one<T,MEAN>(x, rowptr, deg, col, out, w, lane);
}

template<typename T, bool MEAN>
__global__ __launch_bounds__(256) void kaggregate(
    const T* __restrict__ x, const int* __restrict__ rowptr,
    const int* __restrict__ deg, const int* __restrict__ col,
    u16* __restrict__ out, int ndst){
  int gid = blockIdx.x*256 + threadIdx.x;
  int w = gid>>6, lane = gid&63;
  if(w>=ndst) return;
  agg_dispatch<T,MEAN>(x, rowptr, deg, col, out, w, lane);
}

// fused as+us aggregation (independent; one launch)
template<typename T>
__global__ __launch_bounds__(256) void kaggAU(
    const T* __restrict__ xa, const int* __restrict__ rpA,
    const int* __restrict__ degA, const int* __restrict__ colA,
    u16* __restrict__ outA,
    const T* __restrict__ xu, const int* __restrict__ rpU,
    const int* __restrict__ degU, const int* __restrict__ colU,
    u16* __restrict__ outU){
  int gid = blockIdx.x*256 + threadIdx.x;
  int w = gid>>6, lane = gid&63;
  if(w < NSUB)        agg_dispatch<T,false>(xa, rpA, degA, colA, outA, w, lane);
  else if(w < 2*NSUB) agg_dispatch<T,false>(xu, rpU, degU, colU, outU, w-NSUB, lane);
}

// MFMA GEMM (verified R3/R4).
__global__ __launch_bounds__(256) void kgemmM(
    const u16* __restrict__ aggSS, const u16* __restrict__ aggAS,
    const u16* __restrict__ aggUS, const u16* __restrict__ subIn,
    const u16* __restrict__ Wg, const float* __restrict__ bsum,
    u16* __restrict__ subOut){
  __shared__ u16 ldsW[64*264];
  __shared__ float ldsB[64];
  int tid = threadIdx.x;
  const unsigned* wg32 = (const unsigned*)Wg;
  for(int i=tid; i<8192; i+=256){
    int o = i>>7, k2 = i&127;
    ((unsigned*)ldsW)[o*132 + k2] = wg32[i];
  }
  if(tid<64) ldsB[tid] = bsum[tid];
  __syncthreads();
  int lane = tid&63, wid = tid>>6;
  long row0 = (long)blockIdx.x*64 + wid*16;
  const u16* arrs[4] = {aggSS, aggAS, aggUS, subIn};
  v4f acc[4] = {};
  long rowl = row0 + (lane&15);
  int kq = (lane>>4)*8;
  #pragma unroll
  for(int s=0;s<8;s++){
    const u16* ap = arrs[s>>1] + rowl*64 + (s&1)*32 + kq;
    v8s a = *(const v8s*)ap;
    #pragma unroll
    for(int t=0;t<4;t++){
      v8s bf = *(const v8s*)&ldsW[(t*16+(lane&15))*264 + s*32 + kq];
      acc[t] = __builtin_amdgcn_mfma_f32_16x16x32_bf16(a, bf, acc[t], 0,0,0);
    }
  }
  int m0 = (lane>>4)*4;
  #pragma unroll
  for(int t=0;t<4;t++){
    int o = t*16 + (lane&15);
    float bb = ldsB[o];
    #pragma unroll
    for(int r=0;r<4;r++){
      float h = acc[t][r] + bb;
      h = fmaxf(h, 0.f);
      subOut[(row0 + m0 + r)*64 + o] = f2bu(h);
    }
  }
}

// head: softmax(sub @ Wf^T + bf) -> FLOAT32 out
__global__ void khead(const u16* __restrict__ sub, const float* __restrict__ Wf,
                      const float* __restrict__ bfv, float* __restrict__ out, int n){
  __shared__ float w[6*64];
  __shared__ float b[6];
  for(int j=threadIdx.x; j<384; j+=256) w[j]=Wf[j];
  if(threadIdx.x<6) b[threadIdx.x]=bfv[threadIdx.x];
  __syncthreads();
  int i = blockIdx.x*256 + threadIdx.x;
  if(i>=n) return;
  const unsigned int* row = (const unsigned int*)(sub + (size_t)i*HDIM);
  float d0=b[0],d1=b[1],d2=b[2],d3=b[3],d4=b[4],d5=b[5];
  #pragma unroll 8
  for(int k2=0;k2<32;k2++){
    unsigned int v = row[k2];
    float lo = bu2f((u16)(v&0xffffu));
    float hi = bu2f((u16)(v>>16));
    int k = 2*k2;
    d0 += lo*w[0*64+k] + hi*w[0*64+k+1];
    d1 += lo*w[1*64+k] + hi*w[1*64+k+1];
    d2 += lo*w[2*64+k] + hi*w[2*64+k+1];
    d3 += lo*w[3*64+k] + hi*w[3*64+k+1];
    d4 += lo*w[4*64+k] + hi*w[4*64+k+1];
    d5 += lo*w[5*64+k] + hi*w[5*64+k+1];
  }
  float m = fmaxf(fmaxf(fmaxf(d0,d1),fmaxf(d2,d3)),fmaxf(d4,d5));
  float e0=expf(d0-m), e1=expf(d1-m), e2=expf(d2-m);
  float e3=expf(d3-m), e4=expf(d4-m), e5=expf(d5-m);
  float inv = 1.0f/(e0+e1+e2+e3+e4+e5);
  float2* op = (float2*)(out + (size_t)i*6);
  float2 r0; r0.x=e0*inv; r0.y=e1*inv;
  float2 r1; r1.x=e2*inv; r1.y=e3*inv;
  float2 r2; r2.x=e4*inv; r2.y=e5*inv;
  op[0]=r0; op[1]=r1; op[2]=r2;
}

extern "C" void kernel_launch(void* const* d_in, const int* in_sizes, int n_in,
                              void* d_out, int out_size, void* d_ws, size_t ws_size,
                              hipStream_t stream) {
  const float* x_sub = (const float*)d_in[0];
  const float* x_agr = (const float*)d_in[1];
  const float* x_urb = (const float*)d_in[2];
  const float* Wl    = (const float*)d_in[3];
  const float* bl    = (const float*)d_in[4];
  const float* Wr    = (const float*)d_in[5];
  const float* Wf    = (const float*)d_in[6];
  const float* bfv   = (const float*)d_in[7];
  const int* e_ss    = (const int*)d_in[8];
  const int* e_as_s  = (const int*)d_in[9];
  const int* e_as_d  = (const int*)d_in[10];
  const int* e_us    = (const int*)d_in[11];
  float* out = (float*)d_out;

  char* ws = (char*)d_ws;
  size_t off = 0;
  auto alloc = [&](size_t bytes)->void*{
    void* p = ws + off; off += (bytes + 255) & ~(size_t)255; return p;
  };
  u16*  subA   = (u16*) alloc((size_t)NSUB*HDIM*2);
  u16*  subB   = (u16*) alloc((size_t)NSUB*HDIM*2);
  u16*  aggSS  = (u16*) alloc((size_t)NSUB*HDIM*2);
  u16*  aggAS  = (u16*) alloc((size_t)NSUB*HDIM*2);
  u16*  aggUS  = (u16*) alloc((size_t)NSUB*HDIM*2);
  int*  colAS  = (int*)  alloc((size_t)EAS*4);
  int*  colSS  = (int*)  alloc((size_t)ESS*4);
  int*  colUS  = (int*)  alloc((size_t)EUS*4);
  int*  rpAS   = (int*)  alloc((size_t)NSUB*4);
  int*  rpSS   = (int*)  alloc((size_t)NSUB*4);
  int*  rpUS   = (int*)  alloc((size_t)NSUB*4);
  int*  degAS  = (int*)  alloc((size_t)NSUB*4);
  int*  degSS  = (int*)  alloc((size_t)NSUB*4);
  int*  degUS  = (int*)  alloc((size_t)NSUB*4);
  int*  gcur   = (int*)  alloc((size_t)3*NB*4);
  int*  boff   = (int*)  alloc((size_t)3*NB*4);
  u16*  Wg     = (u16*)  alloc((size_t)3*64*256*2);
  float* bsum  = (float*)alloc((size_t)3*64*4);
  size_t off0 = off;
  // partition buffers (dead after ksort) — bf16 agr/urb tables alias them
  unsigned* pAS = (unsigned*)alloc((size_t)NB*CAP_AS*4);
  unsigned* pSS = (unsigned*)alloc((size_t)NB*CAP_SS*4);
  unsigned* pUS = (unsigned*)alloc((size_t)NB*CAP_US*4);
  size_t end_part = off;
  u16* agr16 = (u16*)(ws + off0);
  u16* urb16 = agr16 + (size_t)NAGR*HDIM;
  size_t end_cast = off0 + ((size_t)NAGR+NURB)*HDIM*2;
  size_t need_full = end_part > end_cast ? end_part : end_cast;
  bool bf16_gather = (ws_size >= need_full);
  if(ws_size < end_part){
    fprintf(stderr, "kernel_launch: ws too small: need %zu have %zu\n", end_part, ws_size);
    return;
  }

  // prep
  kcast<<<CDIV(NSUB*HDIM/4,256),256,0,stream>>>((const float4*)x_sub, (uint2*)subA, NSUB*HDIM/4);
  kprep<<<3,256,0,stream>>>(Wl, Wr, bl, Wg, bsum, gcur);

  // bucket partition -> counting sort -> CSR
  kpart<<<NCH_AS+NCH_SS+NCH_US,256,0,stream>>>(e_ss, e_as_s, e_as_d, e_us,
                                               pAS, pSS, pUS, gcur);
  kbscan<<<1,256,0,stream>>>(gcur, boff);
  ksort<<<3*NB,256,0,stream>>>(pAS, pSS, pUS, gcur, boff,
                               colAS, colSS, colUS,
                               rpAS, rpSS, rpUS,
                               degAS, degSS, degUS);

  // one-time agr/urb aggregations (fused as+us)
  const int auBlocks = CDIV(2*NSUB*64,256);
  if(bf16_gather){
    int n4a = NAGR*HDIM/4, n4u = NURB*HDIM/4;
    kcast2<<<CDIV(n4a+n4u,256),256,0,stream>>>((const float4*)x_agr, (uint2*)agr16, n4a,
                                               (const float4*)x_urb, (uint2*)urb16, n4u);
    kaggAU<u16><<<auBlocks,256,0,stream>>>(agr16, rpAS, degAS, colAS, aggAS,
                                           urb16, rpUS, degUS, colUS, aggUS);
  } else {
    kaggAU<float><<<auBlocks,256,0,stream>>>(x_agr, rpAS, degAS, colAS, aggAS,
                                             x_urb, rpUS, degUS, colUS, aggUS);
  }

  const int aggBlocks = CDIV(NSUB*64,256);
  const int gemmBlocks = NSUB/64;
  // layer 0 (ss aggr = sum)
  kaggregate<u16,false><<<aggBlocks,256,0,stream>>>(subA, rpSS, degSS, colSS, aggSS, NSUB);
  kgemmM<<<gemmBlocks,256,0,stream>>>(aggSS, aggAS, aggUS, subA, Wg + 0*16384, bsum + 0*64, subB);
  // layer 1 (ss aggr = mean)
  kaggregate<u16,true><<<aggBlocks,256,0,stream>>>(subB, rpSS, degSS, colSS, aggSS, NSUB);
  kgemmM<<<gemmBlocks,256,0,stream>>>(aggSS, aggAS, aggUS, subB, Wg + 1*16384, bsum + 1*64, subA);
  // layer 2 (ss aggr = mean)
  kaggregate<u16,true><<<aggBlocks,256,0,stream>>>(subA, rpSS, degSS, colSS, aggSS, NSUB);
  kgemmM<<<gemmBlocks,256,0,stream>>>(aggSS, aggAS, aggUS, subA, Wg + 2*16384, bsum + 2*64, subB);

  // head
  khead<<<CDIV(NSUB,256),256,0,stream>>>(subB, Wf, bfv, out, NSUB);
}

// Round 2
// 756.820 us; speedup vs baseline: 1.2093x; 1.1352x over previous
//
#include <hip/hip_runtime.h>
#include <cstdio>
#include <cstdint>

// HeteroGraph 3-layer SAGE on MI355X — R7.
// R6 post-mortem: agg kernels VALU-bound (VALUBusy 88%, hbm 2.9TB/s, time
// -14% only). R7: 2 dsts/wave (halved fixed cost+grid, 2-level reduce),
// zero-row clamp instead of exec-masked loads, imm-offset col loads,
// v_pk_add_f32 packed accumulate. Gather traffic unchanged.

#define NSUB 200000
#define NAGR 400000
#define NURB 200000
#define HDIM 64
#define ESS 2000000
#define EAS 4000000
#define EUS 2000000
#define NB 512
#define CAP_AS 8608
#define CAP_SS 4320
#define CAP_US 4320
#define CHUNK 4096
#define NCH_AS 977
#define NCH_SS 489
#define NCH_US 489
#define COL_SLACK 16384
#define CDIV(a,b) (((a)+(b)-1)/(b))

using u16 = unsigned short;
typedef __attribute__((ext_vector_type(8))) short v8s;
typedef __attribute__((ext_vector_type(4))) float v4f;
typedef __attribute__((ext_vector_type(2))) float v2f;
typedef __attribute__((ext_vector_type(4))) unsigned int v4u;

__device__ __forceinline__ float bu2f(u16 u){
  union { unsigned int i; float f; } c; c.i = ((unsigned int)u) << 16; return c.f;
}
__device__ __forceinline__ u16 f2bu(float x){
  union { float f; unsigned int i; } c; c.f = x;
  unsigned int r = c.i + 0x7fffu + ((c.i >> 16) & 1u);
  return (u16)(r >> 16);
}
__device__ __forceinline__ int bucket_of(int d){
  return (int)(((unsigned long long)(unsigned)d * NB) / NSUB);
}
__device__ __forceinline__ int bucket_base(int b){
  return (int)(((unsigned long long)b * NSUB + NB - 1) / NB);
}

__global__ void kcast(const float4* __restrict__ in, uint2* __restrict__ outp, int n4){
  int i = blockIdx.x*256 + threadIdx.x;
  if(i<n4){
    float4 v = in[i];
    uint2 o;
    o.x = (unsigned int)f2bu(v.x) | ((unsigned int)f2bu(v.y)<<16);
    o.y = (unsigned int)f2bu(v.z) | ((unsigned int)f2bu(v.w)<<16);
    outp[i]=o;
  }
}

// fused cast of x_agr and x_urb -> bf16 (runs AFTER ksort; dst aliases pXX)
// also zeros the appended zero-rows (row NAGR of oa, row NURB of ou).
__global__ void kcast2(const float4* __restrict__ a, uint2* __restrict__ oa, int n4a,
                       const float4* __restrict__ u, uint2* __restrict__ ou, int n4u){
  int i = blockIdx.x*256 + threadIdx.x;
  if(i < n4a){
    float4 v = a[i];
    uint2 o;
    o.x = (unsigned int)f2bu(v.x) | ((unsigned int)f2bu(v.y)<<16);
    o.y = (unsigned int)f2bu(v.z) | ((unsigned int)f2bu(v.w)<<16);
    oa[i]=o;
  } else if(i < n4a + n4u){
    int idx = i - n4a;
    float4 v = u[idx];
    uint2 o;
    o.x = (unsigned int)f2bu(v.x) | ((unsigned int)f2bu(v.y)<<16);
    o.y = (unsigned int)f2bu(v.z) | ((unsigned int)f2bu(v.w)<<16);
    ou[idx]=o;
  } else {
    int k = i - n4a - n4u;
    uint2 z; z.x=0u; z.y=0u;
    if(k < 16) oa[(size_t)n4a + k] = z;         // zero row NAGR (row=16 uint2)
    else if(k < 32) ou[(size_t)n4u + (k-16)] = z; // zero row NURB
  }
}

// Per-layer weights -> bf16 transposed [o][k=256] (+bias sum); zeros gcur
// and the appended zero-rows of subA/subB (row NSUB).
__global__ void kprep(const float* __restrict__ Wl, const float* __restrict__ Wr,
                      const float* __restrict__ bl, u16* __restrict__ Wg,
                      float* __restrict__ bsum, int* __restrict__ gcur,
                      u16* __restrict__ zA, u16* __restrict__ zB){
  int l = blockIdx.x, tid = threadIdx.x;
  for(int i=tid; i<16384; i+=256){
    int o = i>>8, k = i&255, a = k>>6, kk = k&63;
    float v;
    if(a<3) v = Wl[(((size_t)l*3+a)*64+o)*64+kk];
    else    v = Wr[(((size_t)l*3+0)*64+o)*64+kk]
              + Wr[(((size_t)l*3+1)*64+o)*64+kk]
              + Wr[(((size_t)l*3+2)*64+o)*64+kk];
    Wg[((size_t)l*64+o)*256 + k] = f2bu(v);
  }
  if(tid<64) bsum[l*64+tid] = bl[(l*3+0)*64+tid] + bl[(l*3+1)*64+tid] + bl[(l*3+2)*64+tid];
  for(int i=tid;i<NB;i+=256) gcur[l*NB+i]=0;
  if(l==0){
    uint2 z; z.x=0u; z.y=0u;
    if(tid<16)          ((uint2*)(zA + (size_t)NSUB*HDIM))[tid]    = z;
    else if(tid<32)     ((uint2*)(zB + (size_t)NSUB*HDIM))[tid-16] = z;
  }
}

// Fused 3-relation bucket partition (validated R3/R4).
__global__ __launch_bounds__(256) void kpart(
    const int* __restrict__ e_ss, const int* __restrict__ e_as_s,
    const int* __restrict__ e_as_d, const int* __restrict__ e_us,
    unsigned* __restrict__ pAS, unsigned* __restrict__ pSS,
    unsigned* __restrict__ pUS, int* __restrict__ gcur){
  __shared__ int cnt[NB];
  __shared__ int seg[NB];
  int bid = blockIdx.x, tid = threadIdx.x;
  int rel, chunk, cap, Erel;
  const int *sp, *dp; unsigned* part;
  if(bid < NCH_AS){ rel=0; chunk=bid; sp=e_as_s; dp=e_as_d; part=pAS; cap=CAP_AS; Erel=EAS; }
  else if(bid < NCH_AS+NCH_SS){ rel=1; chunk=bid-NCH_AS; sp=e_ss; dp=e_ss+ESS; part=pSS; cap=CAP_SS; Erel=ESS; }
  else { rel=2; chunk=bid-NCH_AS-NCH_SS; sp=e_us; dp=e_us+EUS; part=pUS; cap=CAP_US; Erel=EUS; }
  int m = Erel - chunk*CHUNK; if(m>CHUNK) m=CHUNK;
  for(int i=tid;i<NB;i+=256) cnt[i]=0;
  __syncthreads();
  unsigned pk[16], meta[16];
  #pragma unroll
  for(int j=0;j<16;j++){
    int idx = j*256+tid;
    meta[j] = 0xFFFFFFFFu;
    if(idx < m){
      long i = (long)chunk*CHUNK + idx;
      int s = sp[i], d = dp[i];
      int b = bucket_of(d);
      int r = atomicAdd(&cnt[b],1);
      pk[j] = ((unsigned)s<<9) | (unsigned)(d - bucket_base(b));
      meta[j] = ((unsigned)b<<16) | (unsigned)r;
    }
  }
  __syncthreads();
  for(int q=tid;q<NB;q+=256){
    int c = cnt[q];
    seg[q] = c ? atomicAdd(&gcur[rel*NB+q], c) : 0;
  }
  __syncthreads();
  #pragma unroll
  for(int j=0;j<16;j++){
    if(meta[j]!=0xFFFFFFFFu){
      int b = meta[j]>>16, r = meta[j]&0xFFFF;
      int pos = seg[b] + r;
      if(pos < cap) part[(long)b*cap + pos] = pk[j];
    }
  }
}

// Exclusive scan of clamped bucket sizes -> per-bucket col base offsets.
__global__ void kbscan(const int* __restrict__ gcur, int* __restrict__ boff){
  __shared__ int s1[256];
  int t = threadIdx.x;
  for(int rel=0; rel<3; rel++){
    int cap = (rel==0)?CAP_AS:((rel==1)?CAP_SS:CAP_US);
    int g0 = gcur[rel*NB + 2*t], g1 = gcur[rel*NB + 2*t+1];
    int a0 = g0<cap?g0:cap, a1 = g1<cap?g1:cap;
    s1[t] = a0+a1;
    __syncthreads();
    for(int off=1; off<256; off<<=1){
      int x = s1[t];
      int y = (t>=off)?s1[t-off]:0;
      __syncthreads();
      s1[t] = x+y;
      __syncthreads();
    }
    int e2 = s1[t]-(a0+a1);
    boff[rel*NB + 2*t]   = e2;
    boff[rel*NB + 2*t+1] = e2+a0;
    __syncthreads();
  }
}

// Per-bucket counting sort -> CSR (validated R4).
__global__ __launch_bounds__(256) void ksort(
    const unsigned* __restrict__ pAS, const unsigned* __restrict__ pSS,
    const unsigned* __restrict__ pUS, const int* __restrict__ gcur,
    const int* __restrict__ boff,
    int* __restrict__ colAS, int* __restrict__ colSS, int* __restrict__ colUS,
    int* __restrict__ rpAS, int* __restrict__ rpSS, int* __restrict__ rpUS,
    int* __restrict__ degAS, int* __restrict__ degSS, int* __restrict__ degUS){
  __shared__ int degl[512];
  __shared__ int excl[512];
  __shared__ int cur[512];
  __shared__ int s1[256];
  int bid = blockIdx.x;
  int rel = bid >> 9, b = bid & 511;
  const unsigned* part; int cap; int* col; int* rp; int* deg;
  if(rel==0){ part=pAS; cap=CAP_AS; col=colAS; rp=rpAS; deg=degAS; }
  else if(rel==1){ part=pSS; cap=CAP_SS; col=colSS; rp=rpSS; deg=degSS; }
  else { part=pUS; cap=CAP_US; col=colUS; rp=rpUS; deg=degUS; }
  int tid = threadIdx.x;
  int base_b = bucket_base(b);
  int base_n = (b+1==NB)?NSUB:bucket_base(b+1);
  int width = base_n - base_b;
  int size = gcur[rel*NB+b]; if(size>cap) size=cap;
  int bo = boff[rel*NB+b];
  const unsigned* pb = part + (long)b*cap;
  degl[tid]=0; degl[256+tid]=0;
  __syncthreads();
  for(int i=tid;i<size;i+=256) atomicAdd(&degl[pb[i]&511u],1);
  __syncthreads();
  int a0=degl[2*tid], a1=degl[2*tid+1];
  s1[tid]=a0+a1;
  __syncthreads();
  for(int off=1; off<256; off<<=1){
    int x=s1[tid];
    int y=(tid>=off)?s1[tid-off]:0;
    __syncthreads();
    s1[tid]=x+y;
    __syncthreads();
  }
  int e2 = s1[tid]-(a0+a1);
  excl[2*tid]=e2;     excl[2*tid+1]=e2+a0;
  cur[2*tid]=e2;      cur[2*tid+1]=e2+a0;
  __syncthreads();
  for(int n=tid;n<width;n+=256){
    rp[base_b+n]  = bo + excl[n];
    deg[base_b+n] = degl[n];
  }
  for(int i=tid;i<size;i+=256){
    unsigned p = pb[i];
    int dl = (int)(p&511u);
    int r = atomicAdd(&cur[dl],1);
    col[bo + r] = (int)(p>>9);
  }
}

__device__ __forceinline__ float gather1(const float* x, size_t idx){ return x[idx]; }

// f32 fallback path (only if ws too small for bf16 tables): wave-per-dst.
template<bool MEAN>
__device__ __forceinline__ void agg_one_f32(const float* __restrict__ x,
    const int* __restrict__ rowptr, const int* __restrict__ deg,
    const int* __restrict__ col, u16* __restrict__ out, int w, int lane){
  int s = __builtin_amdgcn_readfirstlane(rowptr[w]);
  int d = __builtin_amdgcn_readfirstlane(deg[w]);
  float acc = 0.f;
  int i=0;
  for(; i+8<=d; i+=8){
    int sj[8];
    #pragma unroll
    for(int j=0;j<8;j++) sj[j]=col[s+i+j];
    float a[8];
    #pragma unroll
    for(int j=0;j<8;j++) a[j]=gather1(x,(size_t)sj[j]*HDIM+lane);
    acc += ((a[0]+a[1])+(a[2]+a[3])) + ((a[4]+a[5])+(a[6]+a[7]));
  }
  for(; i<d; i++) acc += gather1(x,(size_t)col[s+i]*HDIM+lane);
  float sc = 1.f;
  if(MEAN) sc = 1.f/(float)(d>1?d:1);
  out[(size_t)w*HDIM + lane] = f2bu(acc*sc);
}

__global__ __launch_bounds__(256) void kaggAUf(
    const float* __restrict__ xa, const int* __restrict__ rpA,
    const int* __restrict__ degA, const int* __restrict__ colA,
    u16* __restrict__ outA,
    const float* __restrict__ xu, const int* __restrict__ rpU,
    const int* __restrict__ degU, const int* __restrict__ colU,
    u16* __restrict__ outU){
  int gid = blockIdx.x*256 + threadIdx.x;
  int w = gid>>6, lane = gid&63;
  if(w < NSUB)        agg_one_f32<false>(xa, rpA, degA, colA, outA, w, lane);
  else if(w < 2*NSUB) agg_one_f32<false>(xu, rpU, degU, colU, outU, w-NSUB, lane);
}

// R7 paired bf16 gather: 2 dsts per wave (half h=lane>>5), 4 groups of
// 8 lanes per half; group gl handles edges {i+gl+4j}; lane q=lane&7 owns
// feature octet [8q,8q+8). Out-of-degree slots clamp to an all-zero row
// (index zrow) -> unpredicated 16B loads, no zero-init. col arrays have
// COL_SLACK slack so the unguarded col reads stay in-bounds.
template<bool MEAN>
__device__ __forceinline__ void agg_pair(const u16* __restrict__ x,
    const int* __restrict__ rowptr, const int* __restrict__ deg,
    const int* __restrict__ col, u16* __restrict__ out,
    int w0, int lane, int zrow){
  int h  = lane>>5;
  int gl = (lane>>3)&3;
  int q  = lane&7;
  int w  = w0 + h;
  int s  = rowptr[w];
  int d  = deg[w];
  int d0 = __builtin_amdgcn_readlane(d, 0);
  int d1 = __builtin_amdgcn_readlane(d, 32);
  int dm = d0 > d1 ? d0 : d1;
  const u16* xq = x + ((unsigned)q<<3);
  v2f acc[4];
  #pragma unroll
  for(int k=0;k<4;k++){ acc[k].x=0.f; acc[k].y=0.f; }
  for(int i=0; i<dm; i+=16){
    int eb = i + gl;
    const int* cp = col + (s + eb);
    int cj[4];
    #pragma unroll
    for(int j=0;j<4;j++){
      int c = cp[j*4];              // imm-offset loads 0/16/32/48B
      cj[j] = (eb + j*4 < d) ? c : zrow;
    }
    v8s vv[4];
    #pragma unroll
    for(int j=0;j<4;j++)
      vv[j] = *(const v8s*)(xq + (size_t)(unsigned)cj[j]*HDIM);
    #pragma unroll
    for(int j=0;j<4;j++){
      v4u dw = __builtin_bit_cast(v4u, vv[j]);
      #pragma unroll
      for(int k=0;k<4;k++){
        unsigned v = dw[k];
        v2f p;
        p.x = __uint_as_float(v << 16);
        p.y = __uint_as_float(v & 0xffff0000u);
        acc[k] += p;
      }
    }
  }
  #pragma unroll
  for(int k=0;k<4;k++){
    v2f v = acc[k];
    v2f t;
    t.x = __shfl_xor(v.x, 8);  t.y = __shfl_xor(v.y, 8);  v += t;
    t.x = __shfl_xor(v.x, 16); t.y = __shfl_xor(v.y, 16); v += t;
    acc[k] = v;
  }
  float sc = 1.f;
  if(MEAN) sc = 1.f/(float)(d>1?d:1);
  if(gl==0){
    v4u r;
    #pragma unroll
    for(int k=0;k<4;k++)
      r[k] = (unsigned)f2bu(acc[k].x*sc) | ((unsigned)f2bu(acc[k].y*sc)<<16);
    *(v4u*)(out + (size_t)w*HDIM + ((unsigned)q<<3)) = r;
  }
}

template<bool MEAN>
__global__ __launch_bounds__(256) void kaggP(
    const u16* __restrict__ x, const int* __restrict__ rowptr,
    const int* __restrict__ deg, const int* __restrict__ col,
    u16* __restrict__ out, int npair, int zrow){
  int gid = blockIdx.x*256 + threadIdx.x;
  int p = gid>>6, lane = gid&63;
  if(p>=npair) return;
  agg_pair<MEAN>(x, rowptr, deg, col, out, 2*p, lane, zrow);
}

// fused as+us paired aggregation (one launch, NSUB waves)
__global__ __launch_bounds__(256) void kaggAUP(
    const u16* __restrict__ xa, const int* __restrict__ rpA,
    const int* __restrict__ degA, const int* __restrict__ colA,
    u16* __restrict__ outA,
    const u16* __restrict__ xu, const int* __restrict__ rpU,
    const int* __restrict__ degU, const int* __restrict__ colU,
    u16* __restrict__ outU){
  int gid = blockIdx.x*256 + threadIdx.x;
  int p = gid>>6, lane = gid&63;
  if(p < NSUB/2)      agg_pair<false>(xa, rpA, degA, colA, outA, 2*p, lane, NAGR);
  else if(p < NSUB)   agg_pair<false>(xu, rpU, degU, colU, outU, 2*(p-NSUB/2), lane, NURB);
}

// MFMA GEMM (verified R3/R4).
__global__ __launch_bounds__(256) void kgemmM(
    const u16* __restrict__ aggSS, const u16* __restrict__ aggAS,
    const u16* __restrict__ aggUS, const u16* __restrict__ subIn,
    const u16* __restrict__ Wg, const float* __restrict__ bsum,
    u16* __restrict__ subOut){
  __shared__ u16 ldsW[64*264];
  __shared__ float ldsB[64];
  int tid = threadIdx.x;
  const unsigned* wg32 = (const unsigned*)Wg;
  for(int i=tid; i<8192; i+=256){
    int o = i>>7, k2 = i&127;
    ((unsigned*)ldsW)[o*132 + k2] = wg32[i];
  }
  if(tid<64) ldsB[tid] = bsum[tid];
  __syncthreads();
  int lane = tid&63, wid = tid>>6;
  long row0 = (long)blockIdx.x*64 + wid*16;
  const u16* arrs[4] = {aggSS, aggAS, aggUS, subIn};
  v4f acc[4] = {};
  long rowl = row0 + (lane&15);
  int kq = (lane>>4)*8;
  #pragma unroll
  for(int s=0;s<8;s++){
    const u16* ap = arrs[s>>1] + rowl*64 + (s&1)*32 + kq;
    v8s a = *(const v8s*)ap;
    #pragma unroll
    for(int t=0;t<4;t++){
      v8s bf = *(const v8s*)&ldsW[(t*16+(lane&15))*264 + s*32 + kq];
      acc[t] = __builtin_amdgcn_mfma_f32_16x16x32_bf16(a, bf, acc[t], 0,0,0);
    }
  }
  int m0 = (lane>>4)*4;
  #pragma unroll
  for(int t=0;t<4;t++){
    int o = t*16 + (lane&15);
    float bb = ldsB[o];
    #pragma unroll
    for(int r=0;r<4;r++){
      float h = acc[t][r] + bb;
      h = fmaxf(h, 0.f);
      subOut[(row0 + m0 + r)*64 + o] = f2bu(h);
    }
  }
}

// head: softmax(sub @ Wf^T + bf) -> FLOAT32 out
__global__ void khead(const u16* __restrict__ sub, const float* __restrict__ Wf,
                      const float* __restrict__ bfv, float* __restrict__ out, int n){
  __shared__ float w[6*64];
  __shared__ float b[6];
  for(int j=threadIdx.x; j<384; j+=256) w[j]=Wf[j];
  if(threadIdx.x<6) b[threadIdx.x]=bfv[threadIdx.x];
  __syncthreads();
  int i = blockIdx.x*256 + threadIdx.x;
  if(i>=n) return;
  const unsigned int* row = (const unsigned int*)(sub + (size_t)i*HDIM);
  float d0=b[0],d1=b[1],d2=b[2],d3=b[3],d4=b[4],d5=b[5];
  #pragma unroll 8
  for(int k2=0;k2<32;k2++){
    unsigned int v = row[k2];
    float lo = bu2f((u16)(v&0xffffu));
    float hi = bu2f((u16)(v>>16));
    int k = 2*k2;
    d0 += lo*w[0*64+k] + hi*w[0*64+k+1];
    d1 += lo*w[1*64+k] + hi*w[1*64+k+1];
    d2 += lo*w[2*64+k] + hi*w[2*64+k+1];
    d3 += lo*w[3*64+k] + hi*w[3*64+k+1];
    d4 += lo*w[4*64+k] + hi*w[4*64+k+1];
    d5 += lo*w[5*64+k] + hi*w[5*64+k+1];
  }
  float m = fmaxf(fmaxf(fmaxf(d0,d1),fmaxf(d2,d3)),fmaxf(d4,d5));
  float e0=expf(d0-m), e1=expf(d1-m), e2=expf(d2-m);
  float e3=expf(d3-m), e4=expf(d4-m), e5=expf(d5-m);
  float inv = 1.0f/(e0+e1+e2+e3+e4+e5);
  float2* op = (float2*)(out + (size_t)i*6);
  float2 r0; r0.x=e0*inv; r0.y=e1*inv;
  float2 r1; r1.x=e2*inv; r1.y=e3*inv;
  float2 r2; r2.x=e4*inv; r2.y=e5*inv;
  op[0]=r0; op[1]=r1; op[2]=r2;
}

extern "C" void kernel_launch(void* const* d_in, const int* in_sizes, int n_in,
                              void* d_out, int out_size, void* d_ws, size_t ws_size,
                              hipStream_t stream) {
  const float* x_sub = (const float*)d_in[0];
  const float* x_agr = (const float*)d_in[1];
  const float* x_urb = (const float*)d_in[2];
  const float* Wl    = (const float*)d_in[3];
  const float* bl    = (const float*)d_in[4];
  const float* Wr    = (const float*)d_in[5];
  const float* Wf    = (const float*)d_in[6];
  const float* bfv   = (const float*)d_in[7];
  const int* e_ss    = (const int*)d_in[8];
  const int* e_as_s  = (const int*)d_in[9];
  const int* e_as_d  = (const int*)d_in[10];
  const int* e_us    = (const int*)d_in[11];
  float* out = (float*)d_out;

  char* ws = (char*)d_ws;
  size_t off = 0;
  auto alloc = [&](size_t bytes)->void*{
    void* p = ws + off; off += (bytes + 255) & ~(size_t)255; return p;
  };
  u16*  subA   = (u16*) alloc((size_t)(NSUB+1)*HDIM*2);   // +1 zero row
  u16*  subB   = (u16*) alloc((size_t)(NSUB+1)*HDIM*2);   // +1 zero row
  u16*  aggSS  = (u16*) alloc((size_t)NSUB*HDIM*2);
  u16*  aggAS  = (u16*) alloc((size_t)NSUB*HDIM*2);
  u16*  aggUS  = (u16*) alloc((size_t)NSUB*HDIM*2);
  int*  colAS  = (int*)  alloc((size_t)(EAS+COL_SLACK)*4);
  int*  colSS  = (int*)  alloc((size_t)(ESS+COL_SLACK)*4);
  int*  colUS  = (int*)  alloc((size_t)(EUS+COL_SLACK)*4);
  int*  rpAS   = (int*)  alloc((size_t)NSUB*4);
  int*  rpSS   = (int*)  alloc((size_t)NSUB*4);
  int*  rpUS   = (int*)  alloc((size_t)NSUB*4);
  int*  degAS  = (int*)  alloc((size_t)NSUB*4);
  int*  degSS  = (int*)  alloc((size_t)NSUB*4);
  int*  degUS  = (int*)  alloc((size_t)NSUB*4);
  int*  gcur   = (int*)  alloc((size_t)3*NB*4);
  int*  boff   = (int*)  alloc((size_t)3*NB*4);
  u16*  Wg     = (u16*)  alloc((size_t)3*64*256*2);
  float* bsum  = (float*)alloc((size_t)3*64*4);
  size_t off0 = off;
  // partition buffers (dead after ksort) — bf16 agr/urb tables alias them
  unsigned* pAS = (unsigned*)alloc((size_t)NB*CAP_AS*4);
  unsigned* pSS = (unsigned*)alloc((size_t)NB*CAP_SS*4);
  unsigned* pUS = (unsigned*)alloc((size_t)NB*CAP_US*4);
  size_t end_part = off;
  u16* agr16 = (u16*)(ws + off0);
  u16* urb16 = agr16 + (size_t)(NAGR+1)*HDIM;             // +1 zero row each
  size_t end_cast = off0 + ((size_t)NAGR+NURB+2)*HDIM*2;
  size_t need_full = end_part > end_cast ? end_part : end_cast;
  bool bf16_gather = (ws_size >= need_full);
  if(ws_size < end_part){
    fprintf(stderr, "kernel_launch: ws too small: need %zu have %zu\n", end_part, ws_size);
    return;
  }

  // prep
  kcast<<<CDIV(NSUB*HDIM/4,256),256,0,stream>>>((const float4*)x_sub, (uint2*)subA, NSUB*HDIM/4);
  kprep<<<3,256,0,stream>>>(Wl, Wr, bl, Wg, bsum, gcur, subA, subB);

  // bucket partition -> counting sort -> CSR
  kpart<<<NCH_AS+NCH_SS+NCH_US,256,0,stream>>>(e_ss, e_as_s, e_as_d, e_us,
                                               pAS, pSS, pUS, gcur);
  kbscan<<<1,256,0,stream>>>(gcur, boff);
  ksort<<<3*NB,256,0,stream>>>(pAS, pSS, pUS, gcur, boff,
                               colAS, colSS, colUS,
                               rpAS, rpSS, rpUS,
                               degAS, degSS, degUS);

  // one-time agr/urb aggregations (fused as+us)
  if(bf16_gather){
    int n4a = NAGR*HDIM/4, n4u = NURB*HDIM/4;
    kcast2<<<CDIV(n4a+n4u+32,256),256,0,stream>>>((const float4*)x_agr, (uint2*)agr16, n4a,
                                                  (const float4*)x_urb, (uint2*)urb16, n4u);
    kaggAUP<<<NSUB*64/256,256,0,stream>>>(agr16, rpAS, degAS, colAS, aggAS,
                                          urb16, rpUS, degUS, colUS, aggUS);
  } else {
    kaggAUf<<<CDIV(2*NSUB*64,256),256,0,stream>>>(x_agr, rpAS, degAS, colAS, aggAS,
                                                  x_urb, rpUS, degUS, colUS, aggUS);
  }

  const int pairBlocks = (NSUB/2)*64/256;
  const int gemmBlocks = NSUB/64;
  // layer 0 (ss aggr = sum)
  kaggP<false><<<pairBlocks,256,0,stream>>>(subA, rpSS, degSS, colSS, aggSS, NSUB/2, NSUB);
  kgemmM<<<gemmBlocks,256,0,stream>>>(aggSS, aggAS, aggUS, subA, Wg + 0*16384, bsum + 0*64, subB);
  // layer 1 (ss aggr = mean)
  kaggP<true><<<pairBlocks,256,0,stream>>>(subB, rpSS, degSS, colSS, aggSS, NSUB/2, NSUB);
  kgemmM<<<gemmBlocks,256,0,stream>>>(aggSS, aggAS, aggUS, subB, Wg + 1*16384, bsum + 1*64, subA);
  // layer 2 (ss aggr = mean)
  kaggP<true><<<pairBlocks,256,0,stream>>>(subA, rpSS, degSS, colSS, aggSS, NSUB/2, NSUB);
  kgemmM<<<gemmBlocks,256,0,stream>>>(aggSS, aggAS, aggUS, subA, Wg + 2*16384, bsum + 2*64, subB);

  // head
  khead<<<CDIV(NSUB,256),256,0,stream>>>(subB, Wf, bfv, out, NSUB);
}